// Round 3
// baseline (72.657 us; speedup 1.0000x reference)
//
#include <hip/hip_runtime.h>

typedef __attribute__((ext_vector_type(8)))  __bf16 bf16x8;
typedef __attribute__((ext_vector_type(4)))  __bf16 bf16x4;
typedef __attribute__((ext_vector_type(16))) float  f32x16;

constexpr int NG  = 2048;
constexpr int NN  = 64;
constexpr int DD  = 128;
constexpr int KK  = 128;
constexpr int OUTD = 10;

// upper-triangular 32x32 tile list: t -> (ti, tj), ti <= tj
__device__ __host__ inline void tileOf(int t, int& ti, int& tj) {
    if (t < 4)      { ti = 0; tj = t;     }
    else if (t < 7) { ti = 1; tj = t - 3; }
    else if (t < 9) { ti = 2; tj = t - 5; }
    else            { ti = 3; tj = 3;     }
}

// XtL: 64-elem rows, 8 16B-slots -> XOR bits 3-5 with row&7
__device__ inline int xtIdx(int r, int c) { return r * 64  + (c ^ ((r & 7) << 3)); }
// GL: 128-elem rows, 16 16B-slots -> XOR bits 3-6 with row&15
__device__ inline int gIdx (int r, int c) { return r * 128 + (c ^ ((r & 15) << 3)); }

// ---------------------------------------------------------------------------
// Kernel 1a: A[o][f][e] = sum_k Wa[k,f] * W1[o, k*D+e];  c[o][e] = sum_k b[k]*W1[o,k*D+e]
// ---------------------------------------------------------------------------
__global__ __launch_bounds__(128)
void precompute_kernel(const float* __restrict__ Wa,
                       const float* __restrict__ b_att,
                       const float* __restrict__ W1,
                       float* __restrict__ A,
                       float* __restrict__ c)
{
    const int o = blockIdx.x >> 7;
    const int f = blockIdx.x & 127;
    const int e = threadIdx.x;
    const float* __restrict__ W1o = W1 + (size_t)o * (KK * DD);

    float acc = 0.f, cacc = 0.f;
    for (int k = 0; k < KK; ++k) {
        const float w1 = W1o[k * DD + e];
        acc  += Wa[k * DD + f] * w1;
        cacc += b_att[k] * w1;
    }
    A[((size_t)o * DD + f) * DD + e] = acc;
    if (f == 0) c[o * DD + e] = cacc;
}

// ---------------------------------------------------------------------------
// Kernel 1b: symmetrized S packed in 32x32x16 D-fragment order, bf16.
//   S[f,e] = A[f,e]+A[e,f] (f<e) ; A[f,f] (f==e) ; 0 (f>e in diag tiles)
//   Sp[((o*10+t)*64 + lane)*16 + r] = S[ti*32 + (r&3)+8*(r>>2)+4*(lane>>5), tj*32 + (lane&31)]
// ---------------------------------------------------------------------------
__global__ __launch_bounds__(256)
void pack_kernel(const float* __restrict__ A, __bf16* __restrict__ Sp)
{
    const int b = blockIdx.x;
    const int o = b / 10, t = b - o * 10;
    int ti, tj; tileOf(t, ti, tj);
    const int l  = threadIdx.x & 63;
    const int rq = threadIdx.x >> 6;      // 0..3
    const int e  = tj * 32 + (l & 31);
    const float* __restrict__ Ao = A + (size_t)o * DD * DD;

    bf16x4 p;
#pragma unroll
    for (int j = 0; j < 4; ++j) {
        const int f = ti * 32 + j + 8 * rq + 4 * (l >> 5);
        float v;
        if (f < e)       v = Ao[f * DD + e] + Ao[e * DD + f];
        else if (f == e) v = Ao[f * DD + f];
        else             v = 0.f;
        p[j] = (__bf16)v;
    }
    *(bf16x4*)&Sp[(size_t)((o * 10 + t) * 64 + l) * 16 + rq * 4] = p;
}

// ---------------------------------------------------------------------------
// Kernel 2: one block per graph, 512 threads = 8 waves.
// LDS plan (aliased):
//   ldsbuf (32 KB): phase0-1 XtL (first 16 KB) -> phase2-3 GL -> phase4-5 PP (20 KB)
//   sp[8][128] f32 (4 KB): per-(ti,half) column-sum partials
//   sLds[128]: colsum s
// ---------------------------------------------------------------------------
__global__ __launch_bounds__(512, 8)
void graph_kernel(const float* __restrict__ x,
                  const __bf16* __restrict__ Sp,
                  const float* __restrict__ cg,
                  const float* __restrict__ bias1,
                  float* __restrict__ out)
{
    __shared__ __align__(16) __bf16 ldsbuf[DD * DD];   // 32 KB
    __shared__ float sp[8][DD];                        // 4 KB
    __shared__ float sLds[DD];

    __bf16* const XtL = ldsbuf;            // 128 rows x 64 (phase 0-1)
    __bf16* const GL  = ldsbuf;            // 128 x 128     (phase 2-3)
    float*  const PP  = (float*)ldsbuf;    // 10 x 512      (phase 4-5)

    const int g   = blockIdx.x;
    const int tid = threadIdx.x;
    const int w   = tid >> 6;
    const int l   = tid & 63;
    const int l31 = l & 31;
    const int l5  = l >> 5;
    const float* __restrict__ xg = x + (size_t)g * NN * DD;

    // ---- phase 0: load X column-wise, store X^T as bf16 (RNE) ----
    {
        const int f = tid & 127, half = tid >> 7;  // 16 n's per thread
        float v[16];
#pragma unroll
        for (int i = 0; i < 16; ++i) v[i] = xg[(half * 16 + i) * DD + f];
        bf16x8 p0, p1;
#pragma unroll
        for (int i = 0; i < 8; ++i) { p0[i] = (__bf16)v[i]; p1[i] = (__bf16)v[8 + i]; }
        *(bf16x8*)&XtL[xtIdx(f, half * 16)]     = p0;
        *(bf16x8*)&XtL[xtIdx(f, half * 16 + 8)] = p1;
    }
    __syncthreads();

    // ---- phase 1: gram tiles. wave w: ti = w&3, tj = {2*(w>>2), +1} ----
    const int ti  = w & 3;
    const int tj0 = (w >> 2) * 2;
    f32x16 acc0, acc1;
#pragma unroll
    for (int i = 0; i < 16; ++i) { acc0[i] = 0.f; acc1[i] = 0.f; }
    {
        const int arow  = ti  * 32 + l31;
        const int brow0 = tj0 * 32 + l31;
#pragma unroll
        for (int ks = 0; ks < 4; ++ks) {
            const int kc = ks * 16 + l5 * 8;
            bf16x8 a  = *(const bf16x8*)&XtL[xtIdx(arow, kc)];
            bf16x8 b0 = *(const bf16x8*)&XtL[xtIdx(brow0, kc)];
            bf16x8 b1 = *(const bf16x8*)&XtL[xtIdx(brow0 + 32, kc)];
            acc0 = __builtin_amdgcn_mfma_f32_32x32x16_bf16(a, b0, acc0, 0, 0, 0);
            acc1 = __builtin_amdgcn_mfma_f32_32x32x16_bf16(a, b1, acc1, 0, 0, 0);
        }
    }
    __syncthreads();   // XtL reads complete; GL may now overwrite it

    // ---- phase 2: quantize, store G transposed (symmetric) + column partials ----
    {
        float sum0 = 0.f, sum1 = 0.f;
#pragma unroll
        for (int tt = 0; tt < 2; ++tt) {
            const int e = (tj0 + tt) * 32 + l31;       // row of G (transposed write)
#pragma unroll
            for (int g2 = 0; g2 < 4; ++g2) {
                bf16x4 p;
#pragma unroll
                for (int j = 0; j < 4; ++j) {
                    const float av = tt ? acc1[g2 * 4 + j] : acc0[g2 * 4 + j];
                    const float q = rintf(av * 100.f) * 0.01f;
                    p[j] = (__bf16)q;
                    if (tt) sum1 += q; else sum0 += q;
                }
                const int fbase = ti * 32 + g2 * 8 + l5 * 4;
                *(bf16x4*)&GL[gIdx(e, fbase)] = p;
            }
        }
        // column-sum partials: this wave covered G rows [ti*32, ti*32+32), lane half l5
        sp[ti * 2 + l5][tj0 * 32 + l31]       = sum0;
        sp[ti * 2 + l5][(tj0 + 1) * 32 + l31] = sum1;
    }
    __syncthreads();   // G + sp complete

    // ---- phase 2.5 (waves 4,5): gather colsum s ----
    if (w == 4 || w == 5) {
        const int e = (w - 4) * 64 + l;
        float s = 0.f;
#pragma unroll
        for (int i = 0; i < 8; ++i) s += sp[i][e];
        sLds[e] = s;
    }

    // ---- phase 3: H = G*G upper-tri tiles ----
    int hti0, htj0; tileOf(w, hti0, htj0);
    f32x16 hacc0, hacc1;
#pragma unroll
    for (int i = 0; i < 16; ++i) { hacc0[i] = 0.f; hacc1[i] = 0.f; }
    {
        const int ra = hti0 * 32 + l31, rb = htj0 * 32 + l31;
#pragma unroll
        for (int ks = 0; ks < 8; ++ks) {
            const int kc = ks * 16 + l5 * 8;
            bf16x8 a = *(const bf16x8*)&GL[gIdx(ra, kc)];
            bf16x8 b = *(const bf16x8*)&GL[gIdx(rb, kc)];
            hacc0 = __builtin_amdgcn_mfma_f32_32x32x16_bf16(a, b, hacc0, 0, 0, 0);
        }
    }
    if (w < 2) {
        int ti1, tj1; tileOf(8 + w, ti1, tj1);
        const int ra = ti1 * 32 + l31, rb = tj1 * 32 + l31;
#pragma unroll
        for (int ks = 0; ks < 8; ++ks) {
            const int kc = ks * 16 + l5 * 8;
            bf16x8 a = *(const bf16x8*)&GL[gIdx(ra, kc)];
            bf16x8 b = *(const bf16x8*)&GL[gIdx(rb, kc)];
            hacc1 = __builtin_amdgcn_mfma_f32_32x32x16_bf16(a, b, hacc1, 0, 0, 0);
        }
    }
    __syncthreads();   // sLds ready; GL reads done -> PP region free

    // ---- phase 4: contraction with S_pack (+ c.s on wave 0); write partials ----
    {
        float po[OUTD];
#pragma unroll
        for (int o = 0; o < OUTD; ++o) {
            const __bf16* spp = Sp + (size_t)((o * 10 + w) * 64 + l) * 16;
            bf16x8 s0 = *(const bf16x8*)&spp[0];
            bf16x8 s1 = *(const bf16x8*)&spp[8];
            float t = 0.f;
#pragma unroll
            for (int j = 0; j < 8; ++j) t += (float)s0[j] * hacc0[j];
#pragma unroll
            for (int j = 0; j < 8; ++j) t += (float)s1[j] * hacc0[8 + j];
            po[o] = t;
        }
        if (w < 2) {
            const int t2 = 8 + w;
#pragma unroll
            for (int o = 0; o < OUTD; ++o) {
                const __bf16* spp = Sp + (size_t)((o * 10 + t2) * 64 + l) * 16;
                bf16x8 s0 = *(const bf16x8*)&spp[0];
                bf16x8 s1 = *(const bf16x8*)&spp[8];
                float t = 0.f;
#pragma unroll
                for (int j = 0; j < 8; ++j) t += (float)s0[j] * hacc1[j];
#pragma unroll
                for (int j = 0; j < 8; ++j) t += (float)s1[j] * hacc1[8 + j];
                po[o] += t;
            }
        }
        if (w == 0) {
#pragma unroll
            for (int o = 0; o < OUTD; ++o)
                po[o] += cg[o * DD + l] * sLds[l] + cg[o * DD + 64 + l] * sLds[64 + l];
        }
#pragma unroll
        for (int o = 0; o < OUTD; ++o) PP[o * 512 + tid] = po[o];
    }
    __syncthreads();

    // ---- phase 5: 12 reduce instances (o = w on all waves; o = 8,9 on waves 0,1) ----
    {
        const int o = w;
        float4 q0 = *(const float4*)&PP[o * 512 + l * 8];
        float4 q1 = *(const float4*)&PP[o * 512 + l * 8 + 4];
        float v = (q0.x + q0.y) + (q0.z + q0.w) + (q1.x + q1.y) + (q1.z + q1.w);
        v += __shfl_down(v, 32, 64);
        v += __shfl_down(v, 16, 64);
        v += __shfl_down(v, 8, 64);
        v += __shfl_down(v, 4, 64);
        v += __shfl_down(v, 2, 64);
        v += __shfl_down(v, 1, 64);
        if (l == 0) out[(size_t)g * OUTD + o] = v + bias1[o];
    }
    if (w < 2) {
        const int o = 8 + w;
        float4 q0 = *(const float4*)&PP[o * 512 + l * 8];
        float4 q1 = *(const float4*)&PP[o * 512 + l * 8 + 4];
        float v = (q0.x + q0.y) + (q0.z + q0.w) + (q1.x + q1.y) + (q1.z + q1.w);
        v += __shfl_down(v, 32, 64);
        v += __shfl_down(v, 16, 64);
        v += __shfl_down(v, 8, 64);
        v += __shfl_down(v, 4, 64);
        v += __shfl_down(v, 2, 64);
        v += __shfl_down(v, 1, 64);
        if (l == 0) out[(size_t)g * OUTD + o] = v + bias1[o];
    }
}

// ---------------------------------------------------------------------------
extern "C" void kernel_launch(void* const* d_in, const int* in_sizes, int n_in,
                              void* d_out, int out_size, void* d_ws, size_t ws_size,
                              hipStream_t stream)
{
    const float* x     = (const float*)d_in[0];
    const float* Wa    = (const float*)d_in[1];
    const float* b_att = (const float*)d_in[2];
    const float* W1    = (const float*)d_in[3];
    const float* bias1 = (const float*)d_in[4];
    float* out = (float*)d_out;

    float*  A  = (float*)d_ws;                       // 163840 f32 (640 KB)
    float*  c  = A + (size_t)OUTD * DD * DD;         // 1280 f32
    __bf16* Sp = (__bf16*)(c + OUTD * DD);           // 102400 bf16 (200 KB)

    precompute_kernel<<<OUTD * DD, 128, 0, stream>>>(Wa, b_att, W1, A, c);
    pack_kernel<<<100, 256, 0, stream>>>(A, Sp);
    graph_kernel<<<NG, 512, 0, stream>>>(x, Sp, c, bias1, out);
}

// Round 6
// 54.062 us; speedup vs baseline: 1.3439x; 1.3439x over previous
//
#include <hip/hip_runtime.h>

typedef __attribute__((ext_vector_type(8)))  __bf16 bf16x8;
typedef __attribute__((ext_vector_type(4)))  __bf16 bf16x4;
typedef __attribute__((ext_vector_type(16))) float  f32x16;

constexpr int NG  = 2048;
constexpr int NN  = 64;
constexpr int DD  = 128;
constexpr int KK  = 128;
constexpr int OUTD = 10;

// upper-triangular 32x32 tile list: t -> (ti, tj), ti <= tj
__device__ __host__ inline void tileOf(int t, int& ti, int& tj) {
    if (t < 4)      { ti = 0; tj = t;     }
    else if (t < 7) { ti = 1; tj = t - 3; }
    else if (t < 9) { ti = 2; tj = t - 5; }
    else            { ti = 3; tj = 3;     }
}

// XtL: 64-elem rows -> XOR elem bits 3-5 with row&7
__device__ inline int xtIdx(int r, int c) { return r * 64  + (c ^ ((r & 7) << 3)); }
// GL: 128-elem rows -> XOR elem bits 3-6 with row&15
__device__ inline int gIdx (int r, int c) { return r * 128 + (c ^ ((r & 15) << 3)); }

// ---------------------------------------------------------------------------
// Kernel 1a: A[o][f][e] = sum_k Wa[k,f]*W1[o,k*D+e]; c[o][e] = sum_k b[k]*W1[o,k*D+e]
// ---------------------------------------------------------------------------
__global__ __launch_bounds__(128)
void precompute_kernel(const float* __restrict__ Wa,
                       const float* __restrict__ b_att,
                       const float* __restrict__ W1,
                       float* __restrict__ A,
                       float* __restrict__ c)
{
    const int o = blockIdx.x >> 7;
    const int f = blockIdx.x & 127;
    const int e = threadIdx.x;
    const float* __restrict__ W1o = W1 + (size_t)o * (KK * DD);

    float acc = 0.f, cacc = 0.f;
    for (int k = 0; k < KK; ++k) {
        const float w1 = W1o[k * DD + e];
        acc  += Wa[k * DD + f] * w1;
        cacc += b_att[k] * w1;
    }
    A[((size_t)o * DD + f) * DD + e] = acc;
    if (f == 0) c[o * DD + e] = cacc;
}

// ---------------------------------------------------------------------------
// Kernel 1b (round-2-proven): symmetrized S packed in 32x32 D-fragment order,
// bf16, diag-tile upper part zeroed in memory.
//   S[f,e] = A[f,e]+A[e,f] (f<e) ; A[f,f] (f==e) ; 0 (f>e in diag tiles)
//   Sp[((o*10+t)*64 + lane)*16 + r] = S[ti*32 + (r&3)+8*(r>>2)+4*(lane>>5), tj*32 + (lane&31)]
// ---------------------------------------------------------------------------
__global__ __launch_bounds__(256)
void pack_kernel(const float* __restrict__ A, __bf16* __restrict__ Sp)
{
    const int b = blockIdx.x;
    const int o = b / 10, t = b - o * 10;
    int ti, tj; tileOf(t, ti, tj);
    const int l  = threadIdx.x & 63;
    const int rq = threadIdx.x >> 6;      // 0..3
    const int e  = tj * 32 + (l & 31);
    const float* __restrict__ Ao = A + (size_t)o * DD * DD;

    bf16x4 p;
#pragma unroll
    for (int j = 0; j < 4; ++j) {
        const int f = ti * 32 + j + 8 * rq + 4 * (l >> 5);
        float v;
        if (f < e)       v = Ao[f * DD + e] + Ao[e * DD + f];
        else if (f == e) v = Ao[f * DD + f];
        else             v = 0.f;
        p[j] = (__bf16)v;
    }
    *(bf16x4*)&Sp[(size_t)((o * 10 + t) * 64 + l) * 16 + rq * 4] = p;
}

// ---------------------------------------------------------------------------
// Per-graph phases 0-3. Produces colsum sOut[128] and the wave's H-tile
// accumulators hacc0 (tile w) and hacc1 (tile 8+(w-6), waves 6,7).
// ---------------------------------------------------------------------------
__device__ __forceinline__ void process_graph(
    const float* __restrict__ xg,
    __bf16* __restrict__ XtL, __bf16* __restrict__ GL,
    float (*__restrict__ sp)[DD], float* __restrict__ sOut,
    int tid, int w, int l, int l31, int l5,
    f32x16& hacc0, f32x16& hacc1)
{
    // ---- phase 0: load X column-wise, store X^T as bf16 (RNE) ----
    {
        const int f = tid & 127, half = tid >> 7;
#pragma unroll
        for (int ch = 0; ch < 2; ++ch) {
            float v[8];
#pragma unroll
            for (int i = 0; i < 8; ++i) v[i] = xg[(half * 16 + ch * 8 + i) * DD + f];
            bf16x8 p;
#pragma unroll
            for (int i = 0; i < 8; ++i) p[i] = (__bf16)v[i];
            *(bf16x8*)&XtL[xtIdx(f, half * 16 + ch * 8)] = p;
        }
    }
    __syncthreads();

    // ---- phase 1: gram tiles. wave w: ti = w&3, tj = {2*(w>>2), +1} ----
    const int ti  = w & 3;
    const int tj0 = (w >> 2) * 2;
    f32x16 acc0, acc1;
#pragma unroll
    for (int i = 0; i < 16; ++i) { acc0[i] = 0.f; acc1[i] = 0.f; }
    {
        const int arow  = ti  * 32 + l31;
        const int brow0 = tj0 * 32 + l31;
#pragma unroll
        for (int ks = 0; ks < 4; ++ks) {
            const int kc = ks * 16 + l5 * 8;
            bf16x8 a  = *(const bf16x8*)&XtL[xtIdx(arow, kc)];
            bf16x8 b0 = *(const bf16x8*)&XtL[xtIdx(brow0, kc)];
            bf16x8 b1 = *(const bf16x8*)&XtL[xtIdx(brow0 + 32, kc)];
            acc0 = __builtin_amdgcn_mfma_f32_32x32x16_bf16(a, b0, acc0, 0, 0, 0);
            acc1 = __builtin_amdgcn_mfma_f32_32x32x16_bf16(a, b1, acc1, 0, 0, 0);
        }
    }
    __syncthreads();   // XtL reads done; GL may overwrite

    // ---- phase 2: quantize, store G transposed (symmetric) + column partials ----
    {
        float sum0 = 0.f, sum1 = 0.f;
#pragma unroll
        for (int tt = 0; tt < 2; ++tt) {
            const int e = (tj0 + tt) * 32 + l31;       // row of G (transposed write)
#pragma unroll
            for (int g2 = 0; g2 < 4; ++g2) {
                bf16x4 p;
#pragma unroll
                for (int j = 0; j < 4; ++j) {
                    const float av = tt ? acc1[g2 * 4 + j] : acc0[g2 * 4 + j];
                    const float q = rintf(av * 100.f) * 0.01f;
                    p[j] = (__bf16)q;
                    if (tt) sum1 += q; else sum0 += q;
                }
                const int fbase = ti * 32 + g2 * 8 + l5 * 4;
                *(bf16x4*)&GL[gIdx(e, fbase)] = p;
            }
        }
        sp[ti * 2 + l5][tj0 * 32 + l31]       = sum0;
        sp[ti * 2 + l5][(tj0 + 1) * 32 + l31] = sum1;
    }
    __syncthreads();   // G + sp complete

    // ---- phase 2.5 (waves 4,5): gather colsum ----
    if (w == 4 || w == 5) {
        const int e = (w - 4) * 64 + l;
        float s = 0.f;
#pragma unroll
        for (int i = 0; i < 8; ++i) s += sp[i][e];
        sOut[e] = s;
    }

    // ---- phase 3: H = G*G upper-tri tiles (tiles 8,9 on waves 6,7) ----
#pragma unroll
    for (int i = 0; i < 16; ++i) { hacc0[i] = 0.f; hacc1[i] = 0.f; }
    {
        int hti, htj; tileOf(w, hti, htj);
        const int ra = hti * 32 + l31, rb = htj * 32 + l31;
#pragma unroll
        for (int ks = 0; ks < 8; ++ks) {
            const int kc = ks * 16 + l5 * 8;
            bf16x8 a = *(const bf16x8*)&GL[gIdx(ra, kc)];
            bf16x8 b = *(const bf16x8*)&GL[gIdx(rb, kc)];
            hacc0 = __builtin_amdgcn_mfma_f32_32x32x16_bf16(a, b, hacc0, 0, 0, 0);
        }
    }
    if (w >= 6) {
        int ti1, tj1; tileOf(8 + (w - 6), ti1, tj1);
        const int ra = ti1 * 32 + l31, rb = tj1 * 32 + l31;
#pragma unroll
        for (int ks = 0; ks < 8; ++ks) {
            const int kc = ks * 16 + l5 * 8;
            bf16x8 a = *(const bf16x8*)&GL[gIdx(ra, kc)];
            bf16x8 b = *(const bf16x8*)&GL[gIdx(rb, kc)];
            hacc1 = __builtin_amdgcn_mfma_f32_32x32x16_bf16(a, b, hacc1, 0, 0, 0);
        }
    }
    __syncthreads();   // GL reads done (region reusable); sOut visible
}

// ---------------------------------------------------------------------------
// Kernel 2: one block per TWO graphs, 512 threads = 8 waves.
// LDS: ldsraw 40 KB (XtL 16K -> GL 32K -> PP 40K), sp 4 KB, sA/sB 1 KB.
// ---------------------------------------------------------------------------
__global__ __launch_bounds__(512, 4)
void graph_kernel(const float* __restrict__ x,
                  const __bf16* __restrict__ Sp,
                  const float* __restrict__ cg,
                  const float* __restrict__ bias1,
                  float* __restrict__ out)
{
    __shared__ __align__(16) char ldsraw[20 * 512 * 4];   // 40 KB
    __shared__ float sp[8][DD];                           // 4 KB
    __shared__ float sA[DD], sB[DD];

    __bf16* const XtL = (__bf16*)ldsraw;
    __bf16* const GL  = (__bf16*)ldsraw;
    float*  const PP  = (float*)ldsraw;

    const int g0  = blockIdx.x * 2;
    const int g1  = g0 + 1;
    const int tid = threadIdx.x;
    const int w   = tid >> 6;
    const int l   = tid & 63;
    const int l31 = l & 31;
    const int l5  = l >> 5;

    f32x16 hA0, hA1, hB0, hB1;
    process_graph(x + (size_t)g0 * NN * DD, XtL, GL, sp, sA,
                  tid, w, l, l31, l5, hA0, hA1);
    process_graph(x + (size_t)g1 * NN * DD, XtL, GL, sp, sB,
                  tid, w, l, l31, l5, hB0, hB1);

    // ---- phase 4: contraction with Sp (bf16, fragment order; zeros baked) ----
#pragma unroll
    for (int o = 0; o < OUTD; ++o) {
        const __bf16* __restrict__ spp = Sp + (size_t)((o * 10 + w) * 64 + l) * 16;
        const bf16x8 s0 = *(const bf16x8*)&spp[0];
        const bf16x8 s1 = *(const bf16x8*)&spp[8];
        float tA = 0.f, tB = 0.f;
#pragma unroll
        for (int j = 0; j < 8; ++j) {
            const float v = (float)s0[j];
            tA += v * hA0[j];
            tB += v * hB0[j];
        }
#pragma unroll
        for (int j = 0; j < 8; ++j) {
            const float v = (float)s1[j];
            tA += v * hA0[8 + j];
            tB += v * hB0[8 + j];
        }
        if (w >= 6) {   // extra tiles 8,9
            const __bf16* __restrict__ sp2 =
                Sp + (size_t)((o * 10 + 8 + (w - 6)) * 64 + l) * 16;
            const bf16x8 e0 = *(const bf16x8*)&sp2[0];
            const bf16x8 e1 = *(const bf16x8*)&sp2[8];
#pragma unroll
            for (int j = 0; j < 8; ++j) {
                const float v = (float)e0[j];
                tA += v * hA1[j];
                tB += v * hB1[j];
            }
#pragma unroll
            for (int j = 0; j < 8; ++j) {
                const float v = (float)e1[j];
                tA += v * hA1[8 + j];
                tB += v * hB1[8 + j];
            }
        }
        if (w == 0) {
            tA += cg[o * DD + l] * sA[l] + cg[o * DD + 64 + l] * sA[64 + l];
            tB += cg[o * DD + l] * sB[l] + cg[o * DD + 64 + l] * sB[64 + l];
        }
        PP[o * 512 + tid]        = tA;
        PP[(10 + o) * 512 + tid] = tB;
    }
    __syncthreads();

    // ---- phase 5: 20 reduce instances over 8 waves ----
    for (int p = w; p < 2 * OUTD; p += 8) {
        const float4 q0 = *(const float4*)&PP[p * 512 + l * 8];
        const float4 q1 = *(const float4*)&PP[p * 512 + l * 8 + 4];
        float v = (q0.x + q0.y) + (q0.z + q0.w) + (q1.x + q1.y) + (q1.z + q1.w);
        v += __shfl_down(v, 32, 64);
        v += __shfl_down(v, 16, 64);
        v += __shfl_down(v, 8, 64);
        v += __shfl_down(v, 4, 64);
        v += __shfl_down(v, 2, 64);
        v += __shfl_down(v, 1, 64);
        if (l == 0) {
            const int gg = (p < OUTD) ? g0 : g1;
            const int oo = (p < OUTD) ? p : p - OUTD;
            out[(size_t)gg * OUTD + oo] = v + bias1[oo];
        }
    }
}

// ---------------------------------------------------------------------------
extern "C" void kernel_launch(void* const* d_in, const int* in_sizes, int n_in,
                              void* d_out, int out_size, void* d_ws, size_t ws_size,
                              hipStream_t stream)
{
    const float* x     = (const float*)d_in[0];
    const float* Wa    = (const float*)d_in[1];
    const float* b_att = (const float*)d_in[2];
    const float* W1    = (const float*)d_in[3];
    const float* bias1 = (const float*)d_in[4];
    float* out = (float*)d_out;

    float*  A  = (float*)d_ws;                       // 163840 f32 (640 KB)
    float*  c  = A + (size_t)OUTD * DD * DD;         // 1280 f32
    __bf16* Sp = (__bf16*)(c + OUTD * DD);           // 102400 bf16 (200 KB) -> 845 KB total

    precompute_kernel<<<OUTD * DD, 128, 0, stream>>>(Wa, b_att, W1, A, c);
    pack_kernel<<<100, 256, 0, stream>>>(A, Sp);
    graph_kernel<<<NG / 2, 512, 0, stream>>>(x, Sp, c, bias1, out);
}

// Round 7
// 51.297 us; speedup vs baseline: 1.4164x; 1.0539x over previous
//
#include <hip/hip_runtime.h>

typedef __attribute__((ext_vector_type(8)))  __bf16 bf16x8;
typedef __attribute__((ext_vector_type(4)))  __bf16 bf16x4;
typedef __attribute__((ext_vector_type(16))) float  f32x16;

constexpr int NG  = 2048;
constexpr int NN  = 64;
constexpr int DD  = 128;
constexpr int KK  = 128;
constexpr int OUTD = 10;

// upper-triangular 32x32 tile list: t -> (ti, tj), ti <= tj
__device__ __host__ inline void tileOf(int t, int& ti, int& tj) {
    if (t < 4)      { ti = 0; tj = t;     }
    else if (t < 7) { ti = 1; tj = t - 3; }
    else if (t < 9) { ti = 2; tj = t - 5; }
    else            { ti = 3; tj = 3;     }
}

// XtL: 64-elem rows -> XOR elem bits 3-5 with row&7
__device__ inline int xtIdx(int r, int c) { return r * 64  + (c ^ ((r & 7) << 3)); }
// GL: 128-elem rows -> XOR elem bits 3-6 with row&15
__device__ inline int gIdx (int r, int c) { return r * 128 + (c ^ ((r & 15) << 3)); }

// ---------------------------------------------------------------------------
// Kernel 1a: A[o][f][e] = sum_k Wa[k,f]*W1[o,k*D+e]; c[o][e] = sum_k b[k]*W1[o,k*D+e]
// ---------------------------------------------------------------------------
__global__ __launch_bounds__(128)
void precompute_kernel(const float* __restrict__ Wa,
                       const float* __restrict__ b_att,
                       const float* __restrict__ W1,
                       float* __restrict__ A,
                       float* __restrict__ c)
{
    const int o = blockIdx.x >> 7;
    const int f = blockIdx.x & 127;
    const int e = threadIdx.x;
    const float* __restrict__ W1o = W1 + (size_t)o * (KK * DD);

    float acc = 0.f, cacc = 0.f;
    for (int k = 0; k < KK; ++k) {
        const float w1 = W1o[k * DD + e];
        acc  += Wa[k * DD + f] * w1;
        cacc += b_att[k] * w1;
    }
    A[((size_t)o * DD + f) * DD + e] = acc;
    if (f == 0) c[o * DD + e] = cacc;
}

// ---------------------------------------------------------------------------
// Kernel 1b (round-2-proven): symmetrized S packed in 32x32 D-fragment order,
// bf16, diag-tile upper part zeroed in memory.
//   S[f,e] = A[f,e]+A[e,f] (f<e) ; A[f,f] (f==e) ; 0 (f>e in diag tiles)
//   Sp[((o*10+t)*64 + lane)*16 + r] = S[ti*32 + (r&3)+8*(r>>2)+4*(lane>>5), tj*32 + (lane&31)]
// ---------------------------------------------------------------------------
__global__ __launch_bounds__(256)
void pack_kernel(const float* __restrict__ A, __bf16* __restrict__ Sp)
{
    const int b = blockIdx.x;
    const int o = b / 10, t = b - o * 10;
    int ti, tj; tileOf(t, ti, tj);
    const int l  = threadIdx.x & 63;
    const int rq = threadIdx.x >> 6;      // 0..3
    const int e  = tj * 32 + (l & 31);
    const float* __restrict__ Ao = A + (size_t)o * DD * DD;

    bf16x4 p;
#pragma unroll
    for (int j = 0; j < 4; ++j) {
        const int f = ti * 32 + j + 8 * rq + 4 * (l >> 5);
        float v;
        if (f < e)       v = Ao[f * DD + e] + Ao[e * DD + f];
        else if (f == e) v = Ao[f * DD + f];
        else             v = 0.f;
        p[j] = (__bf16)v;
    }
    *(bf16x4*)&Sp[(size_t)((o * 10 + t) * 64 + l) * 16 + rq * 4] = p;
}

// ---------------------------------------------------------------------------
// Per-graph phases 0-3. Produces colsum sOut[128] (waves 2,3), the wave's
// H-tile accumulator hacc0 (tile w), and accumulates extra tiles 8,9 into
// haccX on waves extraBase, extraBase+1 (haccX zero-initialized by caller,
// shared between the two graphs on disjoint wave pairs).
// ---------------------------------------------------------------------------
__device__ __forceinline__ void process_graph(
    const float* __restrict__ xg,
    __bf16* __restrict__ XtL, __bf16* __restrict__ GL,
    float (*__restrict__ sp)[DD], float* __restrict__ sOut,
    int tid, int w, int l, int l31, int l5, int extraBase,
    f32x16& hacc0, f32x16& haccX)
{
    // ---- phase 0: load X column-wise, store X^T as bf16 (RNE) ----
    {
        const int f = tid & 127, half = tid >> 7;
#pragma unroll
        for (int ch = 0; ch < 2; ++ch) {
            float v[8];
#pragma unroll
            for (int i = 0; i < 8; ++i) v[i] = xg[(half * 16 + ch * 8 + i) * DD + f];
            bf16x8 p;
#pragma unroll
            for (int i = 0; i < 8; ++i) p[i] = (__bf16)v[i];
            *(bf16x8*)&XtL[xtIdx(f, half * 16 + ch * 8)] = p;
        }
    }
    __syncthreads();

    // ---- phase 1: gram tiles. wave w: ti = w&3, tj = {2*(w>>2), +1} ----
    const int ti  = w & 3;
    const int tj0 = (w >> 2) * 2;
    f32x16 acc0, acc1;
#pragma unroll
    for (int i = 0; i < 16; ++i) { acc0[i] = 0.f; acc1[i] = 0.f; }
    {
        const int arow  = ti  * 32 + l31;
        const int brow0 = tj0 * 32 + l31;
#pragma unroll
        for (int ks = 0; ks < 4; ++ks) {
            const int kc = ks * 16 + l5 * 8;
            bf16x8 a  = *(const bf16x8*)&XtL[xtIdx(arow, kc)];
            bf16x8 b0 = *(const bf16x8*)&XtL[xtIdx(brow0, kc)];
            bf16x8 b1 = *(const bf16x8*)&XtL[xtIdx(brow0 + 32, kc)];
            acc0 = __builtin_amdgcn_mfma_f32_32x32x16_bf16(a, b0, acc0, 0, 0, 0);
            acc1 = __builtin_amdgcn_mfma_f32_32x32x16_bf16(a, b1, acc1, 0, 0, 0);
        }
    }
    __syncthreads();   // XtL reads done; GL may overwrite

    // ---- phase 2: quantize, store G transposed (symmetric) + column partials ----
    {
        float sum0 = 0.f, sum1 = 0.f;
#pragma unroll
        for (int tt = 0; tt < 2; ++tt) {
            const int e = (tj0 + tt) * 32 + l31;       // row of G (transposed write)
#pragma unroll
            for (int g2 = 0; g2 < 4; ++g2) {
                bf16x4 p;
#pragma unroll
                for (int j = 0; j < 4; ++j) {
                    const float av = tt ? acc1[g2 * 4 + j] : acc0[g2 * 4 + j];
                    const float q = rintf(av * 100.f) * 0.01f;
                    p[j] = (__bf16)q;
                    if (tt) sum1 += q; else sum0 += q;
                }
                const int fbase = ti * 32 + g2 * 8 + l5 * 4;
                *(bf16x4*)&GL[gIdx(e, fbase)] = p;
            }
        }
        sp[ti * 2 + l5][tj0 * 32 + l31]       = sum0;
        sp[ti * 2 + l5][(tj0 + 1) * 32 + l31] = sum1;
    }
    __syncthreads();   // G + sp complete

    // ---- phase 2.5 (waves 2,3): gather colsum ----
    if (w == 2 || w == 3) {
        const int e = (w - 2) * 64 + l;
        float s = 0.f;
#pragma unroll
        for (int i = 0; i < 8; ++i) s += sp[i][e];
        sOut[e] = s;
    }

    // ---- phase 3: H = G*G upper-tri tiles (extras 8,9 on extraBase,+1) ----
#pragma unroll
    for (int i = 0; i < 16; ++i) hacc0[i] = 0.f;
    {
        int hti, htj; tileOf(w, hti, htj);
        const int ra = hti * 32 + l31, rb = htj * 32 + l31;
#pragma unroll
        for (int ks = 0; ks < 8; ++ks) {
            const int kc = ks * 16 + l5 * 8;
            bf16x8 a = *(const bf16x8*)&GL[gIdx(ra, kc)];
            bf16x8 b = *(const bf16x8*)&GL[gIdx(rb, kc)];
            hacc0 = __builtin_amdgcn_mfma_f32_32x32x16_bf16(a, b, hacc0, 0, 0, 0);
        }
    }
    if (w == extraBase || w == extraBase + 1) {
        int ti1, tj1; tileOf(8 + (w - extraBase), ti1, tj1);
        const int ra = ti1 * 32 + l31, rb = tj1 * 32 + l31;
#pragma unroll
        for (int ks = 0; ks < 8; ++ks) {
            const int kc = ks * 16 + l5 * 8;
            bf16x8 a = *(const bf16x8*)&GL[gIdx(ra, kc)];
            bf16x8 b = *(const bf16x8*)&GL[gIdx(rb, kc)];
            haccX = __builtin_amdgcn_mfma_f32_32x32x16_bf16(a, b, haccX, 0, 0, 0);
        }
    }
    __syncthreads();   // GL reads done (region reusable); sOut visible
}

// ---------------------------------------------------------------------------
// Kernel 2: one block per TWO graphs, 512 threads = 8 waves.
// LDS: ldsraw 40 KB (XtL 16K -> GL 32K -> PP 40K), sp 4 KB, sA/sB 1 KB.
// Extra H-tiles: graph A on waves 6,7; graph B on waves 4,5 (shared haccX).
// ---------------------------------------------------------------------------
__global__ __launch_bounds__(512)
void graph_kernel(const float* __restrict__ x,
                  const __bf16* __restrict__ Sp,
                  const float* __restrict__ cg,
                  const float* __restrict__ bias1,
                  float* __restrict__ out)
{
    __shared__ __align__(16) char ldsraw[20 * 512 * 4];   // 40 KB
    __shared__ float sp[8][DD];                           // 4 KB
    __shared__ float sA[DD], sB[DD];

    __bf16* const XtL = (__bf16*)ldsraw;
    __bf16* const GL  = (__bf16*)ldsraw;
    float*  const PP  = (float*)ldsraw;

    const int g0  = blockIdx.x * 2;
    const int g1  = g0 + 1;
    const int tid = threadIdx.x;
    const int w   = tid >> 6;
    const int l   = tid & 63;
    const int l31 = l & 31;
    const int l5  = l >> 5;

    f32x16 hA0, hB0, hX1;
#pragma unroll
    for (int i = 0; i < 16; ++i) hX1[i] = 0.f;

    process_graph(x + (size_t)g0 * NN * DD, XtL, GL, sp, sA,
                  tid, w, l, l31, l5, /*extraBase=*/6, hA0, hX1);
    process_graph(x + (size_t)g1 * NN * DD, XtL, GL, sp, sB,
                  tid, w, l, l31, l5, /*extraBase=*/4, hB0, hX1);

    // ---- phase 4: contraction with Sp (bf16, fragment order; zeros baked) ----
#pragma unroll
    for (int o = 0; o < OUTD; ++o) {
        const __bf16* __restrict__ spp = Sp + (size_t)((o * 10 + w) * 64 + l) * 16;
        const bf16x8 s0 = *(const bf16x8*)&spp[0];
        const bf16x8 s1 = *(const bf16x8*)&spp[8];
        float tA = 0.f, tB = 0.f;
#pragma unroll
        for (int j = 0; j < 8; ++j) {
            const float v = (float)s0[j];
            tA += v * hA0[j];
            tB += v * hB0[j];
        }
#pragma unroll
        for (int j = 0; j < 8; ++j) {
            const float v = (float)s1[j];
            tA += v * hA0[8 + j];
            tB += v * hB0[8 + j];
        }
        if (w >= 4) {   // extra tiles: t2 = 8+(w&1); A on waves 6,7 / B on 4,5
            const __bf16* __restrict__ sp2 =
                Sp + (size_t)((o * 10 + 8 + (w & 1)) * 64 + l) * 16;
            const bf16x8 e0 = *(const bf16x8*)&sp2[0];
            const bf16x8 e1 = *(const bf16x8*)&sp2[8];
            float tx = 0.f;
#pragma unroll
            for (int j = 0; j < 8; ++j) tx += (float)e0[j] * hX1[j];
#pragma unroll
            for (int j = 0; j < 8; ++j) tx += (float)e1[j] * hX1[8 + j];
            if (w >= 6) tA += tx; else tB += tx;
        }
        if (w == 0) {
            tA += cg[o * DD + l] * sA[l] + cg[o * DD + 64 + l] * sA[64 + l];
            tB += cg[o * DD + l] * sB[l] + cg[o * DD + 64 + l] * sB[64 + l];
        }
        PP[o * 512 + tid]        = tA;
        PP[(10 + o) * 512 + tid] = tB;
    }
    __syncthreads();

    // ---- phase 5: 20 reduce instances over 8 waves ----
    for (int p = w; p < 2 * OUTD; p += 8) {
        const float4 q0 = *(const float4*)&PP[p * 512 + l * 8];
        const float4 q1 = *(const float4*)&PP[p * 512 + l * 8 + 4];
        float v = (q0.x + q0.y) + (q0.z + q0.w) + (q1.x + q1.y) + (q1.z + q1.w);
        v += __shfl_down(v, 32, 64);
        v += __shfl_down(v, 16, 64);
        v += __shfl_down(v, 8, 64);
        v += __shfl_down(v, 4, 64);
        v += __shfl_down(v, 2, 64);
        v += __shfl_down(v, 1, 64);
        if (l == 0) {
            const int gg = (p < OUTD) ? g0 : g1;
            const int oo = (p < OUTD) ? p : p - OUTD;
            out[(size_t)gg * OUTD + oo] = v + bias1[oo];
        }
    }
}

// ---------------------------------------------------------------------------
extern "C" void kernel_launch(void* const* d_in, const int* in_sizes, int n_in,
                              void* d_out, int out_size, void* d_ws, size_t ws_size,
                              hipStream_t stream)
{
    const float* x     = (const float*)d_in[0];
    const float* Wa    = (const float*)d_in[1];
    const float* b_att = (const float*)d_in[2];
    const float* W1    = (const float*)d_in[3];
    const float* bias1 = (const float*)d_in[4];
    float* out = (float*)d_out;

    float*  A  = (float*)d_ws;                       // 163840 f32 (640 KB)
    float*  c  = A + (size_t)OUTD * DD * DD;         // 1280 f32
    __bf16* Sp = (__bf16*)(c + OUTD * DD);           // 102400 bf16 (200 KB) -> 845 KB total

    precompute_kernel<<<OUTD * DD, 128, 0, stream>>>(Wa, b_att, W1, A, c);
    pack_kernel<<<100, 256, 0, stream>>>(A, Sp);
    graph_kernel<<<NG / 2, 512, 0, stream>>>(x, Sp, c, bias1, out);
}